// Round 3
// baseline (361.210 us; speedup 1.0000x reference)
//
#include <hip/hip_runtime.h>
#include <hip/hip_bf16.h>
#include <math.h>

#define N_TOK 16384
#define D_MODEL 2048
#define N_EXP 64
#define CAPACITY 640
#define KSPLIT 8
#define KSLICE (D_MODEL / KSPLIT)  // 256
#define BKS 32                     // k per LDS stage
#define XPAD 36                    // padded row (dwords): b128 lane-stride 36 -> conflict-free
#define NREP 8                     // atomic replicas

// ---------------- K0: transpose W[e][k] -> Wt[k][e] -------------------------
__global__ __launch_bounds__(256) void k0_transpose(
    const float* __restrict__ W, float* __restrict__ Wt) {
  const int tid = blockIdx.x * 256 + threadIdx.x;  // 32768 threads
#pragma unroll
  for (int i = 0; i < 4; i++) {
    const int idx = tid + 32768 * i;       // linear over Wt: idx = k*64 + e
    const int e = idx & 63, k = idx >> 6;
    Wt[idx] = W[(size_t)e * D_MODEL + k];  // write coalesced, read L2-gather
  }
}

// ---------------- K1: split-K GEMM, partials[slice][e][token] ---------------
// grid 512 = 8 kslices x 64 token-groups; block 256 thr; thread = 1 token,
// acc[64] over experts; W broadcast via scalar loads (wave-uniform address).
__global__ __launch_bounds__(256, 2) void k1_gemm(
    const float* __restrict__ x, const float* __restrict__ Wt,
    float* __restrict__ part) {
  __shared__ float xs[256][XPAD];  // 36.9 KB

  const int t = threadIdx.x;
  const int ks = blockIdx.x >> 6;   // k-slice (adjacent blocks share Wt slice)
  const int grp = blockIdx.x & 63;  // token group
  const int m0 = grp * 256;
  const int kb = ks * KSLICE;

  float acc[N_EXP];
#pragma unroll
  for (int e = 0; e < N_EXP; e++) acc[e] = 0.f;

  // stage loader: rows (t>>3)+32i, cols (t&7)*4 — 8 float4 per thread
  const float* xp = x + (size_t)(m0 + (t >> 3)) * D_MODEL + kb + (t & 7) * 4;
  float4 pre[8];
#pragma unroll
  for (int i = 0; i < 8; i++)
    pre[i] = *(const float4*)(xp + (size_t)(32 * i) * D_MODEL);

  for (int s = 0; s < KSLICE / BKS; s++) {  // 8 steps
    __syncthreads();
#pragma unroll
    for (int i = 0; i < 8; i++)
      *(float4*)&xs[(t >> 3) + 32 * i][(t & 7) * 4] = pre[i];
    __syncthreads();
    if (s + 1 < KSLICE / BKS) {
#pragma unroll
      for (int i = 0; i < 8; i++)
        pre[i] = *(const float4*)(xp + (size_t)(32 * i) * D_MODEL + (s + 1) * BKS);
    }
    const float4* wt = (const float4*)(Wt + (size_t)(kb + s * BKS) * N_EXP);
    for (int k4 = 0; k4 < BKS / 4; k4++) {
      const float4 xv = *(const float4*)&xs[t][k4 * 4];
#pragma unroll
      for (int kk = 0; kk < 4; kk++) {
        const float xk = (&xv.x)[kk];
        const float4* wtk = wt + (k4 * 4 + kk) * 16;  // uniform -> s_load
#pragma unroll
        for (int e4 = 0; e4 < 16; e4++) {
          const float4 w = wtk[e4];
          acc[e4 * 4 + 0] = fmaf(w.x, xk, acc[e4 * 4 + 0]);
          acc[e4 * 4 + 1] = fmaf(w.y, xk, acc[e4 * 4 + 1]);
          acc[e4 * 4 + 2] = fmaf(w.z, xk, acc[e4 * 4 + 2]);
          acc[e4 * 4 + 3] = fmaf(w.w, xk, acc[e4 * 4 + 3]);
        }
      }
    }
  }
  // coalesced epilogue: part[ks][e][m0+t]
  float* pp = part + (size_t)ks * (N_EXP * N_TOK) + m0 + t;
#pragma unroll
  for (int e = 0; e < N_EXP; e++) pp[(size_t)e * N_TOK] = acc[e];
}

// ---------------- K2: reduce slices + softmax + top2 + z + hist -------------
__global__ __launch_bounds__(64) void k2_softmax(
    const float* __restrict__ part, float* __restrict__ rw_out,
    int* __restrict__ top1, int* __restrict__ top2,
    float* __restrict__ w0p, float* __restrict__ w1p,
    int* __restrict__ histR, float* __restrict__ zR) {
  const int lane = threadIdx.x;
  const int n = blockIdx.x * 64 + lane;
  const int rep = blockIdx.x & (NREP - 1);

  float val[N_EXP];
  {
    const float* p = part + n;
#pragma unroll
    for (int e = 0; e < N_EXP; e++) val[e] = p[(size_t)e * N_TOK];
  }
  for (int s = 1; s < KSPLIT; s++) {
    const float* p = part + (size_t)s * (N_EXP * N_TOK) + n;
#pragma unroll
    for (int e = 0; e < N_EXP; e++) val[e] += p[(size_t)e * N_TOK];
  }

  float m1 = -INFINITY, m2 = -INFINITY, zp = 0.f;
  int i1 = 0, i2 = 0;
#pragma unroll
  for (int e = 0; e < N_EXP; e++) {
    const float vv = val[e];
    zp += vv * vv;
    if (vv > m1) { m2 = m1; i2 = i1; m1 = vv; i1 = e; }
    else if (vv > m2) { m2 = vv; i2 = e; }
  }

  float s = 0.f;
#pragma unroll
  for (int e = 0; e < N_EXP; e++) { val[e] = __expf(val[e] - m1); s += val[e]; }
  const float inv = 1.f / s;
  float* out = rw_out + (size_t)n * N_EXP;
#pragma unroll
  for (int j = 0; j < 16; j++) {
    float4 o = make_float4(val[4 * j] * inv, val[4 * j + 1] * inv,
                           val[4 * j + 2] * inv, val[4 * j + 3] * inv);
    *(float4*)(out + 4 * j) = o;
  }

  const float rw1 = inv;                   // exp(0)*inv
  const float rw2 = __expf(m2 - m1) * inv;
  const float denom = rw1 + rw2 + 1e-8f;
  top1[n] = i1; top2[n] = i2;
  w0p[n] = rw1 / denom; w1p[n] = rw2 / denom;
  atomicAdd(&histR[(rep * N_EXP + i1) * 16], 1);

#pragma unroll
  for (int off = 32; off; off >>= 1) zp += __shfl_xor(zp, off);
  if (lane == 0) atomicAdd(&zR[rep * 16], zp);
}

// ---------------- K3: dispatch mask + per-expert counts ---------------------
__global__ __launch_bounds__(64) void k3_dispatch(
    const int* __restrict__ top1, const int* __restrict__ top2,
    const float* __restrict__ w0p, const float* __restrict__ w1p,
    const int* __restrict__ histR, float* __restrict__ mask_out,
    float* __restrict__ cntR) {
  __shared__ float lc[N_EXP];
  const int lane = threadIdx.x;
  const int n = blockIdx.x * 64 + lane;
  const int rep = blockIdx.x & (NREP - 1);
  lc[lane] = 0.f;
  __syncthreads();

  const int i1 = top1[n], i2 = top2[n];
  const float w0 = w0p[n], w1 = w1p[n];
  int h = 0;
#pragma unroll
  for (int r = 0; r < NREP; r++) h += histR[(r * N_EXP + i2) * 16];
  const bool allowed = h < CAPACITY;
  const float ssum = w0 + (allowed ? w1 : 0.f);
  const float inv = 1.f / (ssum + 1e-8f);
  const float v1 = w0 * inv;
  const float v2 = allowed ? w1 * inv : 0.f;

  float* out = mask_out + (size_t)n * N_EXP;
#pragma unroll
  for (int j = 0; j < 16; j++) {
    float4 o = make_float4(0.f, 0.f, 0.f, 0.f);
    const int e0 = 4 * j;
    if (i1 >= e0 && i1 < e0 + 4) (&o.x)[i1 - e0] = v1;
    if (allowed && i2 >= e0 && i2 < e0 + 4) (&o.x)[i2 - e0] = v2;
    *(float4*)(out + 4 * j) = o;
  }
  atomicAdd(&lc[i1], v1);
  if (allowed) atomicAdd(&lc[i2], v2);
  __syncthreads();
  if (lc[lane] != 0.f) atomicAdd(&cntR[(rep * N_EXP + lane) * 16], lc[lane]);
}

// ---------------- K4: scalar loss -------------------------------------------
__global__ void k4_loss(const float* __restrict__ cntR,
                        const float* __restrict__ zR,
                        float* __restrict__ loss_out) {
  const int lane = threadIdx.x;
  float c = 0.f;
#pragma unroll
  for (int r = 0; r < NREP; r++) c += cntR[(r * N_EXP + lane) * 16];
  const float d = (c - 512.0f) * (1.0f / 16384.0f);
  float v = d * d;
#pragma unroll
  for (int off = 32; off; off >>= 1) v += __shfl_xor(v, off);
  if (lane == 0) {
    float z = 0.f;
#pragma unroll
    for (int r = 0; r < NREP; r++) z += zR[r * 16];
    const float lb = v * (1.0f / 64.0f);
    loss_out[0] = 0.001f * (z * (1.0f / (16384.0f * 64.0f))) + 0.001f * lb;
  }
}

extern "C" void kernel_launch(void* const* d_in, const int* in_sizes, int n_in,
                              void* d_out, int out_size, void* d_ws, size_t ws_size,
                              hipStream_t stream) {
  const float* x = (const float*)d_in[0];
  const float* W = (const float*)d_in[1];
  float* out = (float*)d_out;
  float* rw_out = out;
  float* mask_out = out + (size_t)N_TOK * N_EXP;
  float* loss_out = out + 2 * (size_t)N_TOK * N_EXP;

  char* ws = (char*)d_ws;
  float* part = (float*)ws;                          // 32 MB
  float* Wt = (float*)(ws + 33554432);               // 512 KB
  int* histR = (int*)(ws + 34078720);                // 32 KB
  float* cntR = (float*)(ws + 34111488);             // 32 KB
  float* zR = (float*)(ws + 34144256);               // 512 B
  int* top1 = (int*)(ws + 34144768);
  int* top2 = top1 + N_TOK;
  float* w0p = (float*)(top2 + N_TOK);
  float* w1p = w0p + N_TOK;

  hipMemsetAsync(histR, 0, 32768 + 32768 + 512, stream);
  k0_transpose<<<128, 256, 0, stream>>>(W, Wt);
  k1_gemm<<<KSPLIT * 64, 256, 0, stream>>>(x, Wt, part);
  k2_softmax<<<N_TOK / 64, 64, 0, stream>>>(part, rw_out, top1, top2, w0p, w1p,
                                            histR, zR);
  k3_dispatch<<<N_TOK / 64, 64, 0, stream>>>(top1, top2, w0p, w1p, histR,
                                             mask_out, cntR);
  k4_loss<<<1, 64, 0, stream>>>(cntR, zR, loss_out);
}

// Round 4
// 327.232 us; speedup vs baseline: 1.1038x; 1.1038x over previous
//
#include <hip/hip_runtime.h>
#include <hip/hip_bf16.h>
#include <math.h>

#define N_TOK 16384
#define D_MODEL 2048
#define N_EXP 64
#define CAPACITY 640
#define KSPLIT 8
#define KSLICE (D_MODEL / KSPLIT)  // 256
#define BK 32                      // k per LDS stage
#define XPAD 36                    // 144B row: 16B-aligned, bank-shift 4/row
#define NREP 8                     // atomic replica sets

// ---------------- K1: split-K GEMM, partials[slice][e][token] ---------------
// grid 512 = 8 kslices x 64 token-groups; 256 thr; 8x8 tile per thread.
__global__ __launch_bounds__(256, 2) void k1_gemm(
    const float* __restrict__ x, const float* __restrict__ W,
    float* __restrict__ part) {
  __shared__ float xs[256][XPAD];   // 36 KB, [token][k] natural
  __shared__ float ws[BK][N_EXP];   // 8 KB,  [k][expert]

  const int t = threadIdx.x;
  const int ks = blockIdx.x >> 6;   // k-slice (siblings share W slice)
  const int grp = blockIdx.x & 63;  // token group
  const int m0 = grp * 256;
  const int kb = ks * KSLICE;

  const int tg = t >> 3;            // 0..31: owns tokens tg+32i (strided)
  const int eg = t & 7;             // owns experts eg*8..+7
  const int scol = (t & 7) * 4;     // x-stage col
  const int we = t >> 2;            // W-stage expert 0..63
  const int wp = (t & 3) * 4;       // W-stage k pos

  float acc[8][8] = {};
  const float* xg = x + (size_t)(m0 + tg) * D_MODEL + kb + scol;
  const float* wg = W + (size_t)we * D_MODEL + kb + wp;

  float4 xpre[8];
  float4 wpre[2];
#pragma unroll
  for (int i = 0; i < 8; i++)
    xpre[i] = *(const float4*)(xg + (size_t)(32 * i) * D_MODEL);
  wpre[0] = *(const float4*)(wg);
  wpre[1] = *(const float4*)(wg + 16);

  for (int s = 0; s < KSLICE / BK; s++) {  // 8 stages
    __syncthreads();
#pragma unroll
    for (int i = 0; i < 8; i++)
      *(float4*)&xs[tg + 32 * i][scol] = xpre[i];
    ws[wp + 0][we] = wpre[0].x; ws[wp + 1][we] = wpre[0].y;
    ws[wp + 2][we] = wpre[0].z; ws[wp + 3][we] = wpre[0].w;
    ws[wp + 16][we] = wpre[1].x; ws[wp + 17][we] = wpre[1].y;
    ws[wp + 18][we] = wpre[1].z; ws[wp + 19][we] = wpre[1].w;
    __syncthreads();
    if (s + 1 < KSLICE / BK) {
      const int d = (s + 1) * BK;
#pragma unroll
      for (int i = 0; i < 8; i++)
        xpre[i] = *(const float4*)(xg + (size_t)(32 * i) * D_MODEL + d);
      wpre[0] = *(const float4*)(wg + d);
      wpre[1] = *(const float4*)(wg + d + 16);
    }
    for (int k4 = 0; k4 < BK / 4; k4++) {
      float4 a[8];
#pragma unroll
      for (int i = 0; i < 8; i++)
        a[i] = *(const float4*)&xs[tg + 32 * i][k4 * 4];
      float4 w4[8];
#pragma unroll
      for (int kk = 0; kk < 4; kk++) {
        w4[2 * kk] = *(const float4*)&ws[k4 * 4 + kk][eg * 8];
        w4[2 * kk + 1] = *(const float4*)&ws[k4 * 4 + kk][eg * 8 + 4];
      }
#pragma unroll
      for (int kk = 0; kk < 4; kk++) {
#pragma unroll
        for (int i = 0; i < 8; i++) {
          const float av = (&a[i].x)[kk];
          acc[i][0] = fmaf(av, w4[2 * kk].x, acc[i][0]);
          acc[i][1] = fmaf(av, w4[2 * kk].y, acc[i][1]);
          acc[i][2] = fmaf(av, w4[2 * kk].z, acc[i][2]);
          acc[i][3] = fmaf(av, w4[2 * kk].w, acc[i][3]);
          acc[i][4] = fmaf(av, w4[2 * kk + 1].x, acc[i][4]);
          acc[i][5] = fmaf(av, w4[2 * kk + 1].y, acc[i][5]);
          acc[i][6] = fmaf(av, w4[2 * kk + 1].z, acc[i][6]);
          acc[i][7] = fmaf(av, w4[2 * kk + 1].w, acc[i][7]);
        }
      }
    }
  }
  // part[ks][e][m0 + tok]; tok = tg + 32i -> lanes contiguous per (j,i)
  float* pp = part + (size_t)ks * ((size_t)N_EXP * N_TOK) + m0 + tg;
#pragma unroll
  for (int j = 0; j < 8; j++)
#pragma unroll
    for (int i = 0; i < 8; i++)
      pp[(size_t)(eg * 8 + j) * N_TOK + 32 * i] = acc[i][j];
}

// ---------------- K2: reduce slices + softmax + top2 + z + hist -------------
__global__ __launch_bounds__(256) void k2_softmax(
    const float* __restrict__ part, float* __restrict__ rw_out,
    int* __restrict__ top1, int* __restrict__ top2,
    float* __restrict__ w0p, float* __restrict__ w1p,
    int* __restrict__ histR, float* __restrict__ zR) {
  __shared__ int lhist[N_EXP];
  __shared__ float zred[4];
  const int t = threadIdx.x;
  if (t < N_EXP) lhist[t] = 0;
  __syncthreads();

  const int n = blockIdx.x * 256 + t;
  const int rep = blockIdx.x & (NREP - 1);

  float val[N_EXP];
  {
    const float* p = part + n;
#pragma unroll
    for (int e = 0; e < N_EXP; e++) val[e] = p[(size_t)e * N_TOK];
  }
  for (int s = 1; s < KSPLIT; s++) {
    const float* p = part + (size_t)s * ((size_t)N_EXP * N_TOK) + n;
#pragma unroll
    for (int e = 0; e < N_EXP; e++) val[e] += p[(size_t)e * N_TOK];
  }

  float m1 = -INFINITY, m2 = -INFINITY, zp = 0.f;
  int i1 = 0, i2 = 0;
#pragma unroll
  for (int e = 0; e < N_EXP; e++) {
    const float vv = val[e];
    zp += vv * vv;
    if (vv > m1) { m2 = m1; i2 = i1; m1 = vv; i1 = e; }
    else if (vv > m2) { m2 = vv; i2 = e; }
  }

  float s = 0.f;
#pragma unroll
  for (int e = 0; e < N_EXP; e++) { val[e] = __expf(val[e] - m1); s += val[e]; }
  const float inv = 1.f / s;
  float* out = rw_out + (size_t)n * N_EXP;
#pragma unroll
  for (int j = 0; j < 16; j++) {
    float4 o = make_float4(val[4 * j] * inv, val[4 * j + 1] * inv,
                           val[4 * j + 2] * inv, val[4 * j + 3] * inv);
    *(float4*)(out + 4 * j) = o;
  }

  const float rw1 = inv;                    // exp(0)*inv
  const float rw2 = __expf(m2 - m1) * inv;
  const float denom = rw1 + rw2 + 1e-8f;
  top1[n] = i1; top2[n] = i2;
  w0p[n] = rw1 / denom; w1p[n] = rw2 / denom;
  atomicAdd(&lhist[i1], 1);

#pragma unroll
  for (int off = 32; off; off >>= 1) zp += __shfl_xor(zp, off);
  if ((t & 63) == 0) zred[t >> 6] = zp;
  __syncthreads();
  if (t == 0) atomicAdd(&zR[rep * 16], zred[0] + zred[1] + zred[2] + zred[3]);
  if (t < N_EXP && lhist[t] != 0) atomicAdd(&histR[(rep * N_EXP + t) * 16], lhist[t]);
}

// ---------------- K3: dispatch mask + per-expert counts ---------------------
__global__ __launch_bounds__(256) void k3_dispatch(
    const int* __restrict__ top1, const int* __restrict__ top2,
    const float* __restrict__ w0p, const float* __restrict__ w1p,
    const int* __restrict__ histR, float* __restrict__ mask_out,
    float* __restrict__ cntR) {
  __shared__ float lc[N_EXP];
  const int t = threadIdx.x;
  if (t < N_EXP) lc[t] = 0.f;
  __syncthreads();

  const int n = blockIdx.x * 256 + t;
  const int rep = blockIdx.x & (NREP - 1);
  const int i1 = top1[n], i2 = top2[n];
  const float w0 = w0p[n], w1 = w1p[n];
  int h = 0;
#pragma unroll
  for (int r = 0; r < NREP; r++) h += histR[(r * N_EXP + i2) * 16];
  const bool allowed = h < CAPACITY;
  const float ssum = w0 + (allowed ? w1 : 0.f);
  const float inv = 1.f / (ssum + 1e-8f);
  const float v1 = w0 * inv;
  const float v2 = allowed ? w1 * inv : 0.f;

  float* out = mask_out + (size_t)n * N_EXP;
#pragma unroll
  for (int j = 0; j < 16; j++) {
    float4 o = make_float4(0.f, 0.f, 0.f, 0.f);
    const int e0 = 4 * j;
    if (i1 >= e0 && i1 < e0 + 4) (&o.x)[i1 - e0] = v1;
    if (allowed && i2 >= e0 && i2 < e0 + 4) (&o.x)[i2 - e0] = v2;
    *(float4*)(out + 4 * j) = o;
  }
  atomicAdd(&lc[i1], v1);
  if (allowed) atomicAdd(&lc[i2], v2);
  __syncthreads();
  if (t < N_EXP && lc[t] != 0.f) atomicAdd(&cntR[(rep * N_EXP + t) * 16], lc[t]);
}

// ---------------- K4: scalar loss -------------------------------------------
__global__ void k4_loss(const float* __restrict__ cntR,
                        const float* __restrict__ zR,
                        float* __restrict__ loss_out) {
  const int lane = threadIdx.x;
  float c = 0.f;
#pragma unroll
  for (int r = 0; r < NREP; r++) c += cntR[(r * N_EXP + lane) * 16];
  const float d = (c - 512.0f) * (1.0f / 16384.0f);
  float v = d * d;
#pragma unroll
  for (int off = 32; off; off >>= 1) v += __shfl_xor(v, off);
  if (lane == 0) {
    float z = 0.f;
#pragma unroll
    for (int r = 0; r < NREP; r++) z += zR[r * 16];
    const float lb = v * (1.0f / 64.0f);
    loss_out[0] = 0.001f * (z * (1.0f / (16384.0f * 64.0f))) + 0.001f * lb;
  }
}

extern "C" void kernel_launch(void* const* d_in, const int* in_sizes, int n_in,
                              void* d_out, int out_size, void* d_ws, size_t ws_size,
                              hipStream_t stream) {
  const float* x = (const float*)d_in[0];
  const float* W = (const float*)d_in[1];
  float* out = (float*)d_out;
  float* rw_out = out;
  float* mask_out = out + (size_t)N_TOK * N_EXP;
  float* loss_out = out + 2 * (size_t)N_TOK * N_EXP;

  char* ws = (char*)d_ws;
  float* part = (float*)ws;                 // 8 x 64 x 16384 x 4B = 32 MB
  int* histR = (int*)(ws + 33554432);       // 32 KB (8 reps x 64 x stride16)
  float* cntR = (float*)(ws + 33587200);    // 32 KB
  float* zR = (float*)(ws + 33619968);      // 512 B
  int* top1 = (int*)(ws + 33620480);
  int* top2 = top1 + N_TOK;
  float* w0p = (float*)(top2 + N_TOK);
  float* w1p = w0p + N_TOK;

  hipMemsetAsync(histR, 0, 32768 + 32768 + 512, stream);
  k1_gemm<<<KSPLIT * 64, 256, 0, stream>>>(x, W, part);
  k2_softmax<<<N_TOK / 256, 256, 0, stream>>>(part, rw_out, top1, top2,
                                              w0p, w1p, histR, zR);
  k3_dispatch<<<N_TOK / 256, 256, 0, stream>>>(top1, top2, w0p, w1p, histR,
                                               mask_out, cntR);
  k4_loss<<<1, 64, 0, stream>>>(cntR, zR, loss_out);
}

// Round 5
// 238.585 us; speedup vs baseline: 1.5140x; 1.3716x over previous
//
#include <hip/hip_runtime.h>
#include <hip/hip_bf16.h>
#include <math.h>

#define N_TOK 16384
#define D_MODEL 2048
#define N_EXP 64
#define CAPACITY 640
#define KSPLIT 4
#define KSLICE (D_MODEL / KSPLIT)  // 512
#define BK 32
#define XP 36                      // x LDS pad: 144B rows, 16B-aligned
#define NREP 8

// ---------------- K1: split-K GEMM, partials[slice][token][expert] ----------
// grid 1024 = 4 kslices x 256 tiles; 256 thr; 4x4 tile (64 tok x 64 exp).
__global__ __launch_bounds__(256, 4) void k1_gemm(
    const float* __restrict__ x, const float* __restrict__ W,
    float* __restrict__ part) {
  __shared__ float xs[64][XP];   // [token][k], 9.2 KB
  __shared__ float ws[BK][N_EXP];  // [k][expert], 8 KB

  const int t = threadIdx.x;
  const int ks = blockIdx.x >> 8;    // k-slice 0..3
  const int grp = blockIdx.x & 255;  // tile 0..255
  const int m0 = grp * 64;
  const int kb = ks * KSLICE;

  const int tr = t >> 4;        // token base: owns tr+16i
  const int tc = t & 15;        // expert base: owns 4*tc..+3
  const int xr = t >> 2;        // x-stage row 0..63
  const int xc = (t & 3) * 8;   // x-stage col
  const int we = t & 63;        // w-stage expert
  const int wc = (t >> 6) * 8;  // w-stage k chunk

  const float* xg = x + (size_t)(m0 + xr) * D_MODEL + kb + xc;
  const float* wg = W + (size_t)we * D_MODEL + kb + wc;

  float4 xp0 = *(const float4*)xg, xp1 = *(const float4*)(xg + 4);
  float4 wp0 = *(const float4*)wg, wp1 = *(const float4*)(wg + 4);

  float acc[4][4] = {};

  for (int s = 0; s < KSLICE / BK; s++) {  // 16 stages
    __syncthreads();
    *(float4*)&xs[xr][xc] = xp0;
    *(float4*)&xs[xr][xc + 4] = xp1;
    ws[wc + 0][we] = wp0.x; ws[wc + 1][we] = wp0.y;
    ws[wc + 2][we] = wp0.z; ws[wc + 3][we] = wp0.w;
    ws[wc + 4][we] = wp1.x; ws[wc + 5][we] = wp1.y;
    ws[wc + 6][we] = wp1.z; ws[wc + 7][we] = wp1.w;
    __syncthreads();
    if (s + 1 < KSLICE / BK) {
      const int d = (s + 1) * BK;
      xp0 = *(const float4*)(xg + d); xp1 = *(const float4*)(xg + d + 4);
      wp0 = *(const float4*)(wg + d); wp1 = *(const float4*)(wg + d + 4);
    }
#pragma unroll
    for (int k4 = 0; k4 < BK / 4; k4++) {
      float4 a[4], w4[4];
#pragma unroll
      for (int i = 0; i < 4; i++)
        a[i] = *(const float4*)&xs[tr + 16 * i][k4 * 4];  // broadcast, free
#pragma unroll
      for (int kk = 0; kk < 4; kk++)
        w4[kk] = *(const float4*)&ws[k4 * 4 + kk][tc * 4];  // 2-touch, free
#pragma unroll
      for (int kk = 0; kk < 4; kk++)
#pragma unroll
        for (int i = 0; i < 4; i++) {
          const float av = (&a[i].x)[kk];
          acc[i][0] = fmaf(av, w4[kk].x, acc[i][0]);
          acc[i][1] = fmaf(av, w4[kk].y, acc[i][1]);
          acc[i][2] = fmaf(av, w4[kk].z, acc[i][2]);
          acc[i][3] = fmaf(av, w4[kk].w, acc[i][3]);
        }
    }
  }
  // part[ks][n][e]: 16 lanes x float4 = 256B contiguous per (i)
#pragma unroll
  for (int i = 0; i < 4; i++) {
    float* pp = part + ((size_t)ks * N_TOK + m0 + tr + 16 * i) * N_EXP + tc * 4;
    *(float4*)pp = make_float4(acc[i][0], acc[i][1], acc[i][2], acc[i][3]);
  }
}

// ---------------- K2: wave-per-token softmax + top2 + z + hist --------------
__global__ __launch_bounds__(256) void k2_softmax(
    const float* __restrict__ part, float* __restrict__ rw_out,
    int2* __restrict__ top12, float2* __restrict__ wts,
    int* __restrict__ histR, float* __restrict__ zR) {
  __shared__ float zred[4];
  const int lane = threadIdx.x & 63;
  const int wid = threadIdx.x >> 6;
  const int n = blockIdx.x * 4 + wid;
  const int rep = blockIdx.x & (NREP - 1);

  float v = 0.f;
#pragma unroll
  for (int s = 0; s < KSPLIT; s++)
    v += part[((size_t)s * N_TOK + n) * N_EXP + lane];

  float zp = v * v;
#pragma unroll
  for (int off = 32; off; off >>= 1) zp += __shfl_xor(zp, off);

  float m = v;
#pragma unroll
  for (int off = 32; off; off >>= 1) m = fmaxf(m, __shfl_xor(m, off));
  float p = __expf(v - m);
  float ssum = p;
#pragma unroll
  for (int off = 32; off; off >>= 1) ssum += __shfl_xor(ssum, off);
  const float rw = p / ssum;
  rw_out[(size_t)n * N_EXP + lane] = rw;

  const unsigned long long b1 = __ballot(v == m);
  const int i1 = __builtin_ctzll(b1);
  float v2 = (lane == i1) ? -INFINITY : v;
#pragma unroll
  for (int off = 32; off; off >>= 1) v2 = fmaxf(v2, __shfl_xor(v2, off));
  const unsigned long long b2 = __ballot(v == v2) & ~(1ull << i1);
  const int i2 = __builtin_ctzll(b2);

  const float rw1 = __shfl(rw, i1);
  const float rw2 = __shfl(rw, i2);
  if (lane == 0) {
    const float denom = rw1 + rw2 + 1e-8f;
    top12[n] = make_int2(i1, i2);
    wts[n] = make_float2(rw1 / denom, rw2 / denom);
    atomicAdd(&histR[(rep * N_EXP + i1) * 16], 1);
    zred[wid] = zp;
  }
  __syncthreads();
  if (threadIdx.x == 0)
    atomicAdd(&zR[rep * 16], zred[0] + zred[1] + zred[2] + zred[3]);
}

// ---------------- K3: wave-per-token dispatch mask + counts -----------------
__global__ __launch_bounds__(256) void k3_dispatch(
    const int2* __restrict__ top12, const float2* __restrict__ wts,
    const int* __restrict__ histR, float* __restrict__ mask_out,
    float* __restrict__ cntR) {
  const int lane = threadIdx.x & 63;
  const int wid = threadIdx.x >> 6;
  const int n = blockIdx.x * 4 + wid;
  const int rep = blockIdx.x & (NREP - 1);

  const int2 ij = top12[n];
  const float2 w = wts[n];
  int h = 0;
#pragma unroll
  for (int r = 0; r < NREP; r++) h += histR[(r * N_EXP + ij.y) * 16];
  const bool allowed = h < CAPACITY;
  const float ssum = w.x + (allowed ? w.y : 0.f);
  const float inv = 1.f / (ssum + 1e-8f);
  float val = 0.f;
  if (lane == ij.x) val = w.x * inv;
  else if (allowed && lane == ij.y) val = w.y * inv;
  mask_out[(size_t)n * N_EXP + lane] = val;
  if (val != 0.f) atomicAdd(&cntR[(rep * N_EXP + lane) * 16], val);
}

// ---------------- K4: scalar loss -------------------------------------------
__global__ void k4_loss(const float* __restrict__ cntR,
                        const float* __restrict__ zR,
                        float* __restrict__ loss_out) {
  const int lane = threadIdx.x;
  float c = 0.f;
#pragma unroll
  for (int r = 0; r < NREP; r++) c += cntR[(r * N_EXP + lane) * 16];
  const float d = (c - 512.0f) * (1.0f / 16384.0f);
  float v = d * d;
#pragma unroll
  for (int off = 32; off; off >>= 1) v += __shfl_xor(v, off);
  if (lane == 0) {
    float z = 0.f;
#pragma unroll
    for (int r = 0; r < NREP; r++) z += zR[r * 16];
    const float lb = v * (1.0f / 64.0f);
    loss_out[0] = 0.001f * (z * (1.0f / (16384.0f * 64.0f))) + 0.001f * lb;
  }
}

extern "C" void kernel_launch(void* const* d_in, const int* in_sizes, int n_in,
                              void* d_out, int out_size, void* d_ws, size_t ws_size,
                              hipStream_t stream) {
  const float* x = (const float*)d_in[0];
  const float* W = (const float*)d_in[1];
  float* out = (float*)d_out;
  float* rw_out = out;
  float* mask_out = out + (size_t)N_TOK * N_EXP;
  float* loss_out = out + 2 * (size_t)N_TOK * N_EXP;

  char* ws = (char*)d_ws;
  float* part = (float*)ws;                       // 4 x 16384 x 64 x 4B = 16 MB
  int* histR = (int*)(ws + 16777216);             // 32 KB (8 reps x 64 x s16)
  float* cntR = (float*)(ws + 16777216 + 32768);  // 32 KB
  float* zR = (float*)(ws + 16777216 + 65536);    // 512 B
  int2* top12 = (int2*)(ws + 16777216 + 131072);  // 128 KB
  float2* wts = (float2*)(ws + 16777216 + 262144);// 128 KB

  hipMemsetAsync(histR, 0, 65536 + 512, stream);
  k1_gemm<<<KSPLIT * 256, 256, 0, stream>>>(x, W, part);
  k2_softmax<<<N_TOK / 4, 256, 0, stream>>>(part, rw_out, top12, wts, histR, zR);
  k3_dispatch<<<N_TOK / 4, 256, 0, stream>>>(top12, wts, histR, mask_out, cntR);
  k4_loss<<<1, 64, 0, stream>>>(cntR, zR, loss_out);
}